// Round 5
// baseline (101.625 us; speedup 1.0000x reference)
//
#include <hip/hip_runtime.h>

// x (N,D,L) f32, weight (K,D) f32, scale (1,) f32
// out (N,K,L) f32 = (||x||^2 + ||c||^2 - 2 x.c) / scale^2
#define N_ 32
#define D_ 128
#define L_ 3136
#define K_ 64
#define WSTR 136             // padded W row stride (bf16 elems): 272 B, 16B-aligned
#define WPLANE (K_ * WSTR * 2)   // bytes per W plane (hi or lo) = 17408

typedef short bf16x8 __attribute__((ext_vector_type(8)));
typedef float f32x4  __attribute__((ext_vector_type(4)));

__device__ inline unsigned short f2bf(float f) {       // RNE fp32->bf16 (finite data)
    unsigned u = __float_as_uint(f);
    return (unsigned short)((u + 0x7FFFu + ((u >> 16) & 1u)) >> 16);
}
__device__ inline float bf2f(unsigned short h) {
    return __uint_as_float(((unsigned)h) << 16);
}

// Block: 256 thr = 4 waves. Tile: 64 l x 64 k x TWO n's, full D=128 contraction.
// Split-bf16 (hi/lo) 3-term MFMA; B-fragments reused across both n-streams.
// Grid (49,16) = 784 blocks; W staged once per block (half of R4's prologues).
__global__ __launch_bounds__(256, 4) void enc_mfma_kernel(
    const float* __restrict__ x,
    const float* __restrict__ w,
    const float* __restrict__ scale,
    float* __restrict__ out)
{
    __shared__ __attribute__((aligned(16))) char lds_u[WPLANE * 2]; // W-hi | W-lo, reused as C0 | C1
    __shared__ float lds_csqp[4][64];
    __shared__ float lds_csq[K_];
    __shared__ float lds_xsq[2][64];

    unsigned short* lds_wh = (unsigned short*)lds_u;
    unsigned short* lds_wl = (unsigned short*)(lds_u + WPLANE);
    float* lds_c0 = (float*)lds_u;              // 64*65*4 = 16640 B <= 17408 B
    float* lds_c1 = (float*)(lds_u + WPLANE);

    const int t    = threadIdx.x;   // 0..255
    const int wave = t >> 6;
    const int lane = t & 63;
    const int col  = lane & 15;     // MFMA free-dim lane index
    const int quad = lane >> 4;

    const int n0 = blockIdx.y * 2;
    const int l0 = blockIdx.x * 64;

    // ---- stage W -> bf16 hi/lo in LDS; ||c_k||^2 partials on the side ----
    {
        const int k = t & 63, q = t >> 6;        // row k, d-quarter q
        const float* wr = w + (size_t)k * D_ + q * 32;
        float s = 0.f;
        for (int j = 0; j < 32; j += 4) {
            float4 v = *(const float4*)(wr + j);
            float vv[4] = {v.x, v.y, v.z, v.w};
            __attribute__((aligned(8))) unsigned short hbuf[4], lbuf[4];
#pragma unroll
            for (int c = 0; c < 4; ++c) {
                s = fmaf(vv[c], vv[c], s);
                unsigned short h = f2bf(vv[c]);
                hbuf[c] = h;
                lbuf[c] = f2bf(vv[c] - bf2f(h));
            }
            const int off = k * WSTR + q * 32 + j;
            *(ushort4*)&lds_wh[off] = *(const ushort4*)hbuf;
            *(ushort4*)&lds_wl[off] = *(const ushort4*)lbuf;
        }
        lds_csqp[q][k] = s;
    }
    __syncthreads();
    if (t < K_)
        lds_csq[t] = lds_csqp[0][t] + lds_csqp[1][t] + lds_csqp[2][t] + lds_csqp[3][t];

    // ---- MFMA main loop over 4 d-chunks; B frags shared by both n-streams ----
    // A[m=lane&15][k=quad*8+j] = x[n][d][l0+wave*16+col], d = dc*32+quad*8+j
    const float* xa0 = x + (size_t)n0 * D_ * L_ + l0 + wave * 16 + col;
    const float* xa1 = xa0 + (size_t)D_ * L_;

    f32x4 acc0[4], acc1[4];
#pragma unroll
    for (int kt = 0; kt < 4; ++kt) {
        acc0[kt] = (f32x4){0.f, 0.f, 0.f, 0.f};
        acc1[kt] = (f32x4){0.f, 0.f, 0.f, 0.f};
    }
    float xsq0 = 0.f, xsq1 = 0.f;

#pragma unroll
    for (int dc = 0; dc < 4; ++dc) {
        const size_t doff = (size_t)(dc * 32 + quad * 8) * L_;
        float xv0[8], xv1[8];
#pragma unroll
        for (int j = 0; j < 8; ++j) xv0[j] = xa0[doff + (size_t)j * L_];
#pragma unroll
        for (int j = 0; j < 8; ++j) xv1[j] = xa1[doff + (size_t)j * L_];

        __attribute__((aligned(16))) unsigned short ah0[8], al0[8], ah1[8], al1[8];
#pragma unroll
        for (int j = 0; j < 8; ++j) {
            xsq0 = fmaf(xv0[j], xv0[j], xsq0);
            unsigned short h0 = f2bf(xv0[j]);
            ah0[j] = h0;
            al0[j] = f2bf(xv0[j] - bf2f(h0));
            xsq1 = fmaf(xv1[j], xv1[j], xsq1);
            unsigned short h1 = f2bf(xv1[j]);
            ah1[j] = h1;
            al1[j] = f2bf(xv1[j] - bf2f(h1));
        }
        bf16x8 afh0 = *(const bf16x8*)ah0;
        bf16x8 afl0 = *(const bf16x8*)al0;
        bf16x8 afh1 = *(const bf16x8*)ah1;
        bf16x8 afl1 = *(const bf16x8*)al1;

        const int wb = dc * 32 + quad * 8;       // B[n=col][k=quad*8+j]
#pragma unroll
        for (int kt = 0; kt < 4; ++kt) {
            const int row = kt * 16 + col;
            bf16x8 bh = *(const bf16x8*)&lds_wh[row * WSTR + wb];
            bf16x8 bl = *(const bf16x8*)&lds_wl[row * WSTR + wb];
            acc0[kt] = __builtin_amdgcn_mfma_f32_16x16x32_bf16(afh0, bh, acc0[kt], 0, 0, 0);
            acc0[kt] = __builtin_amdgcn_mfma_f32_16x16x32_bf16(afl0, bh, acc0[kt], 0, 0, 0);
            acc0[kt] = __builtin_amdgcn_mfma_f32_16x16x32_bf16(afh0, bl, acc0[kt], 0, 0, 0);
            acc1[kt] = __builtin_amdgcn_mfma_f32_16x16x32_bf16(afh1, bh, acc1[kt], 0, 0, 0);
            acc1[kt] = __builtin_amdgcn_mfma_f32_16x16x32_bf16(afl1, bh, acc1[kt], 0, 0, 0);
            acc1[kt] = __builtin_amdgcn_mfma_f32_16x16x32_bf16(afh1, bl, acc1[kt], 0, 0, 0);
        }
    }

    // ---- ||x||^2 butterfly over quads (lane holds 32 of 128 d's) ----
    xsq0 += __shfl_xor(xsq0, 16, 64);
    xsq0 += __shfl_xor(xsq0, 32, 64);
    xsq1 += __shfl_xor(xsq1, 16, 64);
    xsq1 += __shfl_xor(xsq1, 32, 64);
    if (quad == 0) {
        lds_xsq[0][wave * 16 + col] = xsq0;
        lds_xsq[1][wave * 16 + col] = xsq1;
    }

    __syncthreads();   // all W ds_reads done; xsq written

    // ---- C tiles -> LDS (reuse W planes), [k][l] stride 65 (conflict-free) ----
    // D layout: col(lane&15)=k free dim, row(quad*4+reg)=l free dim  [m89-verified]
#pragma unroll
    for (int kt = 0; kt < 4; ++kt) {
        const int kk = kt * 16 + col;
#pragma unroll
        for (int r = 0; r < 4; ++r) {
            const int ll = wave * 16 + quad * 4 + r;
            lds_c0[kk * 65 + ll] = acc0[kt][r];
            lds_c1[kk * 65 + ll] = acc1[kt][r];
        }
    }
    __syncthreads();

    // ---- fused epilogue, coalesced 256B/wave stores ----
    const float sc = scale[0];
    const float inv_s2 = 1.0f / (sc * sc);
#pragma unroll
    for (int nn = 0; nn < 2; ++nn) {
        const float* lc = nn ? lds_c1 : lds_c0;
        float* op = out + (size_t)(n0 + nn) * K_ * L_ + l0;
#pragma unroll
        for (int it = 0; it < 16; ++it) {
            const int idx = it * 256 + t;
            const int kk = idx >> 6, ll = idx & 63;
            op[(size_t)kk * L_ + ll] =
                (lds_xsq[nn][ll] + lds_csq[kk] - 2.0f * lc[kk * 65 + ll]) * inv_s2;
        }
    }
}

extern "C" void kernel_launch(void* const* d_in, const int* in_sizes, int n_in,
                              void* d_out, int out_size, void* d_ws, size_t ws_size,
                              hipStream_t stream) {
    const float* x     = (const float*)d_in[0];
    const float* w     = (const float*)d_in[1];
    const float* scale = (const float*)d_in[2];
    float* out = (float*)d_out;

    dim3 grid(L_ / 64, N_ / 2);   // (49, 16) = 784 blocks, no tail
    enc_mfma_kernel<<<grid, 256, 0, stream>>>(x, w, scale, out);
}

// Round 6
// 100.973 us; speedup vs baseline: 1.0065x; 1.0065x over previous
//
#include <hip/hip_runtime.h>

// x (N,D,L) f32, weight (K,D) f32, scale (1,) f32
// out (N,K,L) f32 = (||x||^2 + ||c||^2 - 2 x.c) / scale^2
#define N_ 32
#define D_ 128
#define L_ 3136
#define K_ 64

typedef short bf16x8 __attribute__((ext_vector_type(8)));
typedef float f32x4  __attribute__((ext_vector_type(4)));

__device__ inline unsigned short f2bf(float f) {       // RNE fp32->bf16 (finite data)
    unsigned u = __float_as_uint(f);
    return (unsigned short)((u + 0x7FFFu + ((u >> 16) & 1u)) >> 16);
}
__device__ inline float bf2f(unsigned short h) {
    return __uint_as_float(((unsigned)h) << 16);
}

// ---------------- prep: W -> fragment-ordered bf16 hi/lo planes + ||c||^2 ----------------
// Fragment entry e = (dc*4+kt)*64 + lane holds 8 ushorts:
//   W[kt*16 + (lane&15)][dc*32 + (lane>>4)*8 + j], j = 0..7
// This is exactly the per-lane B-operand order for mfma_f32_16x16x32_bf16, so the
// main kernel's LDS reads are lane-linear (conflict-free) and staging is a flat copy.
__global__ __launch_bounds__(64) void prep_kernel(
    const float* __restrict__ w,
    unsigned short* __restrict__ whi,
    unsigned short* __restrict__ wlo,
    float* __restrict__ csq)
{
    const int b = blockIdx.x, lane = threadIdx.x;
    if (b < 16) {
        const int dc = b >> 2, kt = b & 3;
        const int row = kt * 16 + (lane & 15);
        const int d0  = dc * 32 + (lane >> 4) * 8;
        const float* src = w + row * D_ + d0;
        __attribute__((aligned(16))) unsigned short h[8], l[8];
#pragma unroll
        for (int j = 0; j < 8; ++j) {
            float v = src[j];
            h[j] = f2bf(v);
            l[j] = f2bf(v - bf2f(h[j]));
        }
        const size_t off = (size_t)(b * 64 + lane) * 8;
        *(ushort4*)(whi + off)     = *(const ushort4*)(h);
        *(ushort4*)(whi + off + 4) = *(const ushort4*)(h + 4);
        *(ushort4*)(wlo + off)     = *(const ushort4*)(l);
        *(ushort4*)(wlo + off + 4) = *(const ushort4*)(l + 4);
    } else {           // block 16: ||c_k||^2
        const float* wr = w + lane * D_;
        float s = 0.f;
#pragma unroll
        for (int d = 0; d < D_; d += 4) {
            float4 v = *(const float4*)(wr + d);
            s = fmaf(v.x, v.x, s); s = fmaf(v.y, v.y, s);
            s = fmaf(v.z, v.z, s); s = fmaf(v.w, v.w, s);
        }
        csq[lane] = s;
    }
}

// ---------------- main: 64 l x 64 k x one n per block, split-bf16 3-term MFMA ----------------
__global__ __launch_bounds__(256, 4) void enc_mfma_kernel(
    const float* __restrict__ x,
    const unsigned short* __restrict__ whi,
    const unsigned short* __restrict__ wlo,
    const float* __restrict__ csqg,
    const float* __restrict__ scale,
    float* __restrict__ out)
{
    __shared__ __attribute__((aligned(16))) unsigned short lds_w[2 * 8192]; // hi | lo, 32 KB
    __shared__ float lds_csq[K_];
    __shared__ float lds_xsq[64];
    float* lds_c = (float*)lds_w;   // epilogue C-tile reuse: 64*65*4 = 16640 B <= 32768 B

    const int t    = threadIdx.x;
    const int wave = t >> 6;
    const int lane = t & 63;
    const int col  = lane & 15;
    const int quad = lane >> 4;
    const int n    = blockIdx.y;
    const int l0   = blockIdx.x * 64;

    // ---- stage W frags (2 x 16 KB) + csq via global_load_lds (zero VALU, flat copy) ----
#pragma unroll
    for (int i = 0; i < 8; ++i) {
        const int c = wave * 8 + i;                       // chunk 0..31, wave-uniform
        const unsigned short* g =
            (c < 16 ? whi + (size_t)c * 512 : wlo + (size_t)(c - 16) * 512) + lane * 8;
        __builtin_amdgcn_global_load_lds(
            (const __attribute__((address_space(1))) unsigned int*)g,
            (__attribute__((address_space(3))) unsigned int*)&lds_w[c * 512],
            16, 0, 0);
    }
    if (wave == 0) {
        __builtin_amdgcn_global_load_lds(
            (const __attribute__((address_space(1))) unsigned int*)(csqg + lane),
            (__attribute__((address_space(3))) unsigned int*)lds_csq,
            4, 0, 0);
    }
    __syncthreads();   // vmcnt(0) drain: all W frags + csq resident

    // ---- MFMA main loop: A[m=lane&15][k=quad*8+j] = x[n][dc*32+quad*8+j][l0+wave*16+col] ----
    const float* xa = x + (size_t)n * D_ * L_ + l0 + wave * 16 + col;

    f32x4 acc[4];
#pragma unroll
    for (int kt = 0; kt < 4; ++kt) acc[kt] = (f32x4){0.f, 0.f, 0.f, 0.f};
    float xsq = 0.f;

#pragma unroll
    for (int dc = 0; dc < 4; ++dc) {
        const float* xp = xa + (size_t)(dc * 32 + quad * 8) * L_;
        float xv[8];
#pragma unroll
        for (int j = 0; j < 8; ++j) xv[j] = xp[(size_t)j * L_];

        __attribute__((aligned(16))) unsigned short ah[8], al[8];
#pragma unroll
        for (int j = 0; j < 8; ++j) {
            xsq = fmaf(xv[j], xv[j], xsq);
            unsigned short h = f2bf(xv[j]);
            ah[j] = h;
            al[j] = f2bf(xv[j] - bf2f(h));
        }
        bf16x8 afh = *(const bf16x8*)ah;
        bf16x8 afl = *(const bf16x8*)al;

#pragma unroll
        for (int kt = 0; kt < 4; ++kt) {
            const int fo = ((dc * 4 + kt) * 64 + lane) * 8;   // lane-linear: conflict-free b128
            bf16x8 bh = *(const bf16x8*)&lds_w[fo];
            bf16x8 bl = *(const bf16x8*)&lds_w[8192 + fo];
            acc[kt] = __builtin_amdgcn_mfma_f32_16x16x32_bf16(afh, bh, acc[kt], 0, 0, 0);
            acc[kt] = __builtin_amdgcn_mfma_f32_16x16x32_bf16(afl, bh, acc[kt], 0, 0, 0);
            acc[kt] = __builtin_amdgcn_mfma_f32_16x16x32_bf16(afh, bl, acc[kt], 0, 0, 0);
        }
    }

    // ---- ||x||^2 butterfly over quads (lane holds 32 of 128 d's) ----
    xsq += __shfl_xor(xsq, 16, 64);
    xsq += __shfl_xor(xsq, 32, 64);
    if (quad == 0) lds_xsq[wave * 16 + col] = xsq;

    __syncthreads();   // all W ds_reads done; xsq visible; lds_w now reusable

    // ---- C tile -> LDS, [k][l] stride 65 (conflict-free transpose) ----
    // D layout: col(lane&15) = k free dim, row(quad*4+reg) = l free dim  [m89-verified]
#pragma unroll
    for (int kt = 0; kt < 4; ++kt) {
        const int kk = kt * 16 + col;
#pragma unroll
        for (int r = 0; r < 4; ++r) {
            const int ll = wave * 16 + quad * 4 + r;
            lds_c[kk * 65 + ll] = acc[kt][r];
        }
    }
    __syncthreads();

    // ---- fused epilogue, coalesced 256 B/wave stores ----
    const float sc = scale[0];
    const float inv_s2 = 1.0f / (sc * sc);
    float* op = out + (size_t)n * K_ * L_ + l0;
#pragma unroll
    for (int it = 0; it < 16; ++it) {
        const int idx = it * 256 + t;
        const int kk = idx >> 6, ll = idx & 63;
        op[(size_t)kk * L_ + ll] =
            (lds_xsq[ll] + lds_csq[kk] - 2.0f * lds_c[kk * 65 + ll]) * inv_s2;
    }
}

extern "C" void kernel_launch(void* const* d_in, const int* in_sizes, int n_in,
                              void* d_out, int out_size, void* d_ws, size_t ws_size,
                              hipStream_t stream) {
    const float* x     = (const float*)d_in[0];
    const float* w     = (const float*)d_in[1];
    const float* scale = (const float*)d_in[2];
    float* out = (float*)d_out;

    // d_ws carve: [0,16K) W-hi frags, [16K,32K) W-lo frags, [32K,+256) csq
    unsigned short* whi = (unsigned short*)d_ws;
    unsigned short* wlo = (unsigned short*)((char*)d_ws + 16384);
    float*          csq = (float*)((char*)d_ws + 32768);

    prep_kernel<<<17, 64, 0, stream>>>(w, whi, wlo, csq);
    dim3 grid(L_ / 64, N_);   // (49, 32) = 1568 blocks, no tail
    enc_mfma_kernel<<<grid, 256, 0, stream>>>(x, whi, wlo, csq, scale, out);
}

// Round 7
// 97.880 us; speedup vs baseline: 1.0383x; 1.0316x over previous
//
#include <hip/hip_runtime.h>

// x (N,D,L) f32, weight (K,D) f32, scale (1,) f32
// out (N,K,L) f32 = (||x||^2 + ||c||^2 - 2 x.c) / scale^2
#define N_ 32
#define D_ 128
#define L_ 3136
#define K_ 64

typedef _Float16 f16x8 __attribute__((ext_vector_type(8)));
typedef float    f32x4 __attribute__((ext_vector_type(4)));

// ---------------- prep: W -> fragment-ordered fp16 plane + ||c||^2 ----------------
// Fragment entry e = (dc*4+kt)*64 + lane holds 8 fp16:
//   W[kt*16 + (lane&15)][dc*32 + (lane>>4)*8 + j], j = 0..7
// = per-lane B-operand order for mfma_f32_16x16x32_f16: main kernel stages with a
// flat lane-ordered copy (global_load_lds) and reads lane-linearly (conflict-free).
__global__ __launch_bounds__(64) void prep_kernel(
    const float* __restrict__ w,
    unsigned short* __restrict__ wh,
    float* __restrict__ csq)
{
    const int b = blockIdx.x, lane = threadIdx.x;
    if (b < 16) {
        const int dc = b >> 2, kt = b & 3;
        const int row = kt * 16 + (lane & 15);
        const int d0  = dc * 32 + (lane >> 4) * 8;
        const float* src = w + row * D_ + d0;
        __attribute__((aligned(16))) unsigned short h[8];
#pragma unroll
        for (int j = 0; j < 8; ++j) {
            _Float16 v = (_Float16)src[j];              // RNE f32->f16
            h[j] = *(const unsigned short*)&v;
        }
        const size_t off = (size_t)(b * 64 + lane) * 8;
        *(ushort4*)(wh + off)     = *(const ushort4*)(h);
        *(ushort4*)(wh + off + 4) = *(const ushort4*)(h + 4);
    } else {           // block 16: ||c_k||^2 (fp32, exact)
        const float* wr = w + lane * D_;
        float s = 0.f;
#pragma unroll
        for (int d = 0; d < D_; d += 4) {
            float4 v = *(const float4*)(wr + d);
            s = fmaf(v.x, v.x, s); s = fmaf(v.y, v.y, s);
            s = fmaf(v.z, v.z, s); s = fmaf(v.w, v.w, s);
        }
        csq[lane] = s;
    }
}

// ---------------- main: 64 l x 64 k x one n per block, single-fp16 MFMA ----------------
// LDS 16.6 KB, VGPR-lean, one barrier, direct float4 stores from acc.
__global__ __launch_bounds__(256, 6) void enc_mfma_kernel(
    const float* __restrict__ x,
    const unsigned short* __restrict__ wh,
    const float* __restrict__ csqg,
    const float* __restrict__ scale,
    float* __restrict__ out)
{
    __shared__ __attribute__((aligned(16))) unsigned short lds_w[8192]; // 16 KB W frags
    __shared__ float lds_csq[K_];

    const int t    = threadIdx.x;
    const int wave = t >> 6;
    const int lane = t & 63;
    const int col  = lane & 15;
    const int quad = lane >> 4;
    const int n    = blockIdx.y;
    const int l0   = blockIdx.x * 64;

    // ---- stage W frags (16 KB) + csq via global_load_lds (flat lane-ordered copy) ----
#pragma unroll
    for (int i = 0; i < 4; ++i) {
        const int c = wave * 4 + i;                        // chunk 0..15, wave-uniform
        __builtin_amdgcn_global_load_lds(
            (const __attribute__((address_space(1))) unsigned int*)(wh + (size_t)c * 512 + lane * 8),
            (__attribute__((address_space(3))) unsigned int*)&lds_w[c * 512],
            16, 0, 0);
    }
    if (wave == 0) {
        __builtin_amdgcn_global_load_lds(
            (const __attribute__((address_space(1))) unsigned int*)(csqg + lane),
            (__attribute__((address_space(3))) unsigned int*)lds_csq,
            4, 0, 0);
    }
    __syncthreads();   // W + csq resident; only barrier in the kernel

    // ---- MFMA loop: A[m=lane&15][k=quad*8+j] = x[n][dc*32+quad*8+j][l0+wave*16+col] ----
    const float* xa = x + (size_t)n * D_ * L_ + l0 + wave * 16 + col;

    f32x4 acc[4];
#pragma unroll
    for (int kt = 0; kt < 4; ++kt) acc[kt] = (f32x4){0.f, 0.f, 0.f, 0.f};
    float xsq = 0.f;

#pragma unroll
    for (int dc = 0; dc < 4; ++dc) {
        const float* xp = xa + (size_t)(dc * 32 + quad * 8) * L_;
        float xv[8];
#pragma unroll
        for (int j = 0; j < 8; ++j) xv[j] = xp[(size_t)j * L_];

        union { f16x8 v; _Float16 e[8]; } af;
#pragma unroll
        for (int j = 0; j < 8; ++j) {
            xsq = fmaf(xv[j], xv[j], xsq);     // exact fp32 ||x||^2
            af.e[j] = (_Float16)xv[j];         // RNE f32->f16
        }

#pragma unroll
        for (int kt = 0; kt < 4; ++kt) {
            const int fo = ((dc * 4 + kt) * 64 + lane) * 8;  // lane-linear, conflict-free b128
            f16x8 bf = *(const f16x8*)&lds_w[fo];
            acc[kt] = __builtin_amdgcn_mfma_f32_16x16x32_f16(af.v, bf, acc[kt], 0, 0, 0);
        }
    }

    // ---- ||x||^2 full reduce over quads; then fetch the 4 cols this lane stores ----
    xsq += __shfl_xor(xsq, 16, 64);
    xsq += __shfl_xor(xsq, 32, 64);            // every lane: xsq for its own col
    float xs[4];
#pragma unroll
    for (int r = 0; r < 4; ++r)
        xs[r] = __shfl(xsq, quad * 4 + r, 64); // value for col = quad*4+r (from quad-0 lane)

    // ---- epilogue: fuse terms, direct float4 stores from acc ----
    // D layout: col(lane&15)=k, row(quad*4+r)=l  => acc[kt] holds 4 consecutive l's
    const float sc = scale[0];
    const float inv_s2 = 1.0f / (sc * sc);
    float* op = out + (size_t)n * K_ * L_ + l0 + wave * 16 + quad * 4;
#pragma unroll
    for (int kt = 0; kt < 4; ++kt) {
        const float cs = lds_csq[kt * 16 + col];   // same-address across quads: broadcast
        float4 v;
        v.x = (xs[0] + cs - 2.0f * acc[kt][0]) * inv_s2;
        v.y = (xs[1] + cs - 2.0f * acc[kt][1]) * inv_s2;
        v.z = (xs[2] + cs - 2.0f * acc[kt][2]) * inv_s2;
        v.w = (xs[3] + cs - 2.0f * acc[kt][3]) * inv_s2;
        *(float4*)(op + (size_t)(kt * 16 + col) * L_) = v;
    }
}

extern "C" void kernel_launch(void* const* d_in, const int* in_sizes, int n_in,
                              void* d_out, int out_size, void* d_ws, size_t ws_size,
                              hipStream_t stream) {
    const float* x     = (const float*)d_in[0];
    const float* w     = (const float*)d_in[1];
    const float* scale = (const float*)d_in[2];
    float* out = (float*)d_out;

    // d_ws carve: [0,16K) W fp16 frags, [16K,+256) csq
    unsigned short* wh  = (unsigned short*)d_ws;
    float*          csq = (float*)((char*)d_ws + 16384);

    prep_kernel<<<17, 64, 0, stream>>>(w, wh, csq);
    dim3 grid(L_ / 64, N_);   // (49, 32) = 1568 blocks, no tail
    enc_mfma_kernel<<<grid, 256, 0, stream>>>(x, wh, csq, scale, out);
}